// Round 2
// baseline (6624.406 us; speedup 1.0000x reference)
//
#include <hip/hip_runtime.h>
#include <hip/hip_bf16.h>

using bf16 = __hip_bfloat16;
using bf16x8 = __attribute__((ext_vector_type(8))) short;   // 8 bf16 = 4 VGPRs
using f32x4  = __attribute__((ext_vector_type(4))) float;

#define S_LEN 256
#define NBATCH 32
#define HDIM 1024

// ---------------------------------------------------------------------------
// Convert x (f32, [n][s][d]) -> xT (bf16, [s][n][d]).
// One block per (n,s) row; coalesced f32 reads, coalesced bf16 writes.
// ---------------------------------------------------------------------------
__global__ __launch_bounds__(256) void convert_x(const float* __restrict__ x,
                                                 bf16* __restrict__ xT) {
    const int p = blockIdx.x;          // p = n*256 + s
    const int n = p >> 8;
    const int s = p & 255;
    const float* src = x + (size_t)p * 1024;
    bf16* dst = xT + (size_t)(s * NBATCH + n) * 1024;
#pragma unroll
    for (int j = 0; j < 4; j++) {
        const int d = threadIdx.x + j * 256;
        dst[d] = (bf16)src[d];
    }
}

// ---------------------------------------------------------------------------
// Convert + transpose: 8 matrices of 1024x1024, f32 in, bf16 out,
// out[g][c][r] = in[g][r][c]
// ---------------------------------------------------------------------------
__global__ __launch_bounds__(256) void convert_transpose_1024(const float* __restrict__ in,
                                                              bf16* __restrict__ out) {
    __shared__ float t[32][33];
    const int g  = blockIdx.z;
    const float* A = in  + (size_t)g * 1024 * 1024;
    bf16*        B = out + (size_t)g * 1024 * 1024;
    const int c0 = blockIdx.x * 32;
    const int r0 = blockIdx.y * 32;
    const int tx = threadIdx.x, ty = threadIdx.y;   // (32, 8)
#pragma unroll
    for (int j = 0; j < 32; j += 8)
        t[ty + j][tx] = A[(size_t)(r0 + ty + j) * 1024 + c0 + tx];
    __syncthreads();
#pragma unroll
    for (int j = 0; j < 32; j += 8)
        B[(size_t)(c0 + ty + j) * 1024 + r0 + tx] = (bf16)t[tx][ty + j];
}

// ---------------------------------------------------------------------------
// One time step, both directions, projection fused.
// grid = 128 blocks: dir = bi>>6, col tile = (bi&63)*16. Wave = gate.
// pre[n][c] = sum_k xT[s][n][k]*Wih[g'][k][col] + sum_k h[n][k]*Whh[g'][k][col]
// computed via MFMA 16x16x32 (2 row-frags x 2 matrices), then LDS gate
// exchange + fused cell update. h bf16 ping-pong, c fp32 (block-private).
// ---------------------------------------------------------------------------
__global__ __launch_bounds__(256) void lstm_step(const bf16* __restrict__ xT,
                                                 const bf16* __restrict__ wihT,
                                                 const bf16* __restrict__ whhT,
                                                 const float* __restrict__ mask,
                                                 const float* __restrict__ bias,
                                                 const bf16* __restrict__ h_in,
                                                 bf16* __restrict__ h_out,
                                                 float* __restrict__ cbuf,
                                                 float* __restrict__ out,
                                                 int t) {
    __shared__ float pre_s[4][32][16];
    const int bi   = blockIdx.x;
    const int dir  = bi >> 6;
    const int col0 = (bi & 63) << 4;
    const int g    = threadIdx.x >> 6;        // gate 0..3 (f,i,o,c)
    const int lane = threadIdx.x & 63;
    const int r    = lane & 15;
    const int q    = lane >> 4;
    const int s_idx = dir ? (S_LEN - 1 - t) : t;

    const bf16* Ah = h_in + (size_t)dir * NBATCH * HDIM;                       // [32][1024]
    const bf16* Ax = xT + (size_t)s_idx * NBATCH * HDIM;                       // [32][1024]
    const bf16* Bh = whhT + (size_t)((dir * 4 + g) * 1024 + col0 + r) * 1024;  // B^T row
    const bf16* Bx = wihT + (size_t)((dir * 4 + g) * 1024 + col0 + r) * 1024;

    f32x4 acc0 = {}, acc1 = {};
    for (int k0 = 0; k0 < 1024; k0 += 32) {
        const int ko = k0 + q * 8;
        bf16x8 bh = *(const bf16x8*)(Bh + ko);
        bf16x8 bx = *(const bf16x8*)(Bx + ko);
        bf16x8 ah0 = *(const bf16x8*)(Ah + (size_t)r * 1024 + ko);
        bf16x8 ah1 = *(const bf16x8*)(Ah + (size_t)(16 + r) * 1024 + ko);
        bf16x8 ax0 = *(const bf16x8*)(Ax + (size_t)r * 1024 + ko);
        bf16x8 ax1 = *(const bf16x8*)(Ax + (size_t)(16 + r) * 1024 + ko);
        acc0 = __builtin_amdgcn_mfma_f32_16x16x32_bf16(ah0, bh, acc0, 0, 0, 0);
        acc1 = __builtin_amdgcn_mfma_f32_16x16x32_bf16(ah1, bh, acc1, 0, 0, 0);
        acc0 = __builtin_amdgcn_mfma_f32_16x16x32_bf16(ax0, bx, acc0, 0, 0, 0);
        acc1 = __builtin_amdgcn_mfma_f32_16x16x32_bf16(ax1, bx, acc1, 0, 0, 0);
    }
    // D mapping: col = lane&15 (output col), row = q*4 + rr (batch row)
#pragma unroll
    for (int rr = 0; rr < 4; rr++) {
        pre_s[g][q * 4 + rr][r]      = acc0[rr];
        pre_s[g][16 + q * 4 + rr][r] = acc1[rr];
    }
    __syncthreads();

    // cell update: 32 rows x 16 cols = 512 items / 256 threads
    const int c  = threadIdx.x & 15;
    const int n0 = threadIdx.x >> 4;   // 0..15
    const int gbase = (dir * 4) * 1024 + col0 + c;
#pragma unroll
    for (int nn = 0; nn < 2; nn++) {
        const int n = n0 + nn * 16;
        const float pf = pre_s[0][n][c] + bias[gbase];
        const float pi = pre_s[1][n][c] + bias[gbase + 1024];
        const float po = pre_s[2][n][c] + bias[gbase + 2048];
        const float pc = pre_s[3][n][c] + bias[gbase + 3072];
        const float f  = 1.f / (1.f + expf(-pf));
        const float i  = 1.f / (1.f + expf(-pi));
        const float o  = 1.f / (1.f + expf(-po));
        const float ct = tanhf(pc);
        const size_t cidx = (size_t)(dir * NBATCH + n) * HDIM + col0 + c;
        const float cnew = f * cbuf[cidx] + i * ct;
        cbuf[cidx] = cnew;                       // c updated regardless of mask (ref semantics)
        const float hnew = o * tanhf(cnew);
        const float mt = mask[n * S_LEN + s_idx];
        const float hprev = (float)h_in[cidx];
        const float hcar = (mt == 0.f) ? hprev : hnew;
        h_out[cidx] = (bf16)hcar;
        out[(size_t)(n * S_LEN + s_idx) * 2048 + dir * 1024 + col0 + c] = hcar * mt;
        if (t == S_LEN - 1) {
            out[(size_t)NBATCH * S_LEN * 2048 + n * 2048 + dir * 1024 + col0 + c] = hcar;
        }
    }
}

// ---------------------------------------------------------------------------
// Workspace layout (bytes), total ~50.9 MB:
//   [0,          16777216)  xT    bf16 [256 s][32 n][1024 d]
//   [16777216,   33554432)  wihT  bf16 [8 g][1024 h][1024 d]
//   [33554432,   50331648)  whhT  bf16 [8 g][1024 h][1024 k]
//   [50331648,   50593792)  hbuf  bf16 [2 parity][2 dir][32][1024]
//   [50593792,   50855936)  cbuf  f32  [2 dir][32][1024]
// ---------------------------------------------------------------------------
extern "C" void kernel_launch(void* const* d_in, const int* in_sizes, int n_in,
                              void* d_out, int out_size, void* d_ws, size_t ws_size,
                              hipStream_t stream) {
    const float* x    = (const float*)d_in[0];
    const float* mask = (const float*)d_in[1];
    const float* wih  = (const float*)d_in[2];
    const float* whh  = (const float*)d_in[3];
    const float* bias = (const float*)d_in[4];
    float* out = (float*)d_out;

    char* ws = (char*)d_ws;
    bf16*  xT   = (bf16*)(ws);
    bf16*  wihT = (bf16*)(ws + 16777216);
    bf16*  whhT = (bf16*)(ws + 33554432);
    bf16*  hbuf = (bf16*)(ws + 50331648);
    float* cbuf = (float*)(ws + 50593792);

    // zero h (both parities) and c
    hipMemsetAsync(ws + 50331648, 0, 524288, stream);

    convert_x<<<NBATCH * S_LEN, 256, 0, stream>>>(x, xT);
    dim3 tb(32, 8);
    convert_transpose_1024<<<dim3(32, 32, 8), tb, 0, stream>>>(wih, wihT);
    convert_transpose_1024<<<dim3(32, 32, 8), tb, 0, stream>>>(whh, whhT);

    for (int t = 0; t < S_LEN; t++) {
        bf16* hin  = hbuf + (size_t)(t & 1) * 2 * NBATCH * HDIM;
        bf16* hout = hbuf + (size_t)((t + 1) & 1) * 2 * NBATCH * HDIM;
        lstm_step<<<128, 256, 0, stream>>>(xT, wihT, whhT, mask, bias,
                                           hin, hout, cbuf, out, t);
    }
}